// Round 1
// baseline (818.552 us; speedup 1.0000x reference)
//
#include <hip/hip_runtime.h>
#include <hip/hip_bf16.h>

// Sizes (fixed by the problem)
// B=8, N=1024, hidden=256, heads H=4, d_head D=64, entity_dim=31, merged=35

// ---------------------------------------------------------------------------
// k_proj: merged one-hot projection + mask + my-idx
// block = 256 threads (one output column each), grid = B*N
__global__ __launch_bounds__(256) void k_proj(
    const float* __restrict__ agents, const int* __restrict__ my_id,
    const float* __restrict__ Wp, const float* __restrict__ bp,
    float* __restrict__ proj, float* __restrict__ mask, int* __restrict__ idx)
{
  int blk = blockIdx.x;
  int b = blk >> 10, n = blk & 1023;
  __shared__ float arow[32];
  int t = threadIdx.x;
  if (t < 31) arow[t] = agents[((size_t)(b * 1024 + n)) * 31 + t];
  __syncthreads();
  float id = arow[0];
  int npc = (int)arow[1];
  float acc = bp[t] + id * Wp[t] + Wp[(1 + npc) * 256 + t];
#pragma unroll
  for (int c = 2; c < 31; ++c) acc += arow[c] * Wp[(4 + c) * 256 + t];
  proj[((size_t)(b * 1024 + n)) * 256 + t] = acc;
  if (t == 0) {
    mask[b * 1024 + n] = (id != 0.f) ? 1.f : 0.f;
    if (id == (float)my_id[b]) atomicMin(&idx[b], n);
  }
}

// ---------------------------------------------------------------------------
// Generic fp32 GEMM: C[M x 256] = A[M x K] * B[K x 256] (+bias), M = 8192
// 64x64 tile, 256 threads, 4x4 micro-tile per thread, K chunked by 64.
__global__ __launch_bounds__(256) void k_gemm(
    const float* __restrict__ A, const float* __restrict__ B,
    const float* __restrict__ bias, float* __restrict__ C, int K)
{
  __shared__ float As[64][68];  // [k][i]
  __shared__ float Bs[64][68];  // [k][j]
  int tid = threadIdx.x;
  int bi = blockIdx.x >> 2;   // 0..127
  int bj = blockIdx.x & 3;    // 0..3
  int i0 = bi << 6, j0 = bj << 6;
  int ti4 = (tid & 15) << 2;  // 0..60
  int tj4 = (tid >> 4) << 2;  // 0..60
  int r = tid >> 2;           // 0..63
  int c0 = (tid & 3) << 4;    // 0,16,32,48
  float acc[4][4];
#pragma unroll
  for (int a = 0; a < 4; ++a)
#pragma unroll
    for (int q = 0; q < 4; ++q) acc[a][q] = 0.f;

  for (int k0 = 0; k0 < K; k0 += 64) {
    const float4* Ap4 = (const float4*)(A + (size_t)(i0 + r) * K + k0 + c0);
    float4 aa0 = Ap4[0], aa1 = Ap4[1], aa2 = Ap4[2], aa3 = Ap4[3];
    As[c0 + 0][r] = aa0.x; As[c0 + 1][r] = aa0.y; As[c0 + 2][r] = aa0.z; As[c0 + 3][r] = aa0.w;
    As[c0 + 4][r] = aa1.x; As[c0 + 5][r] = aa1.y; As[c0 + 6][r] = aa1.z; As[c0 + 7][r] = aa1.w;
    As[c0 + 8][r] = aa2.x; As[c0 + 9][r] = aa2.y; As[c0 +10][r] = aa2.z; As[c0 +11][r] = aa2.w;
    As[c0 +12][r] = aa3.x; As[c0 +13][r] = aa3.y; As[c0 +14][r] = aa3.z; As[c0 +15][r] = aa3.w;
    const float4* Bp4 = (const float4*)(B + (size_t)(k0 + r) * 256 + j0 + c0);
    float4 bb0 = Bp4[0], bb1 = Bp4[1], bb2 = Bp4[2], bb3 = Bp4[3];
    *(float4*)&Bs[r][c0 + 0]  = bb0;
    *(float4*)&Bs[r][c0 + 4]  = bb1;
    *(float4*)&Bs[r][c0 + 8]  = bb2;
    *(float4*)&Bs[r][c0 + 12] = bb3;
    __syncthreads();
#pragma unroll
    for (int k = 0; k < 64; ++k) {
      float4 av = *(const float4*)&As[k][ti4];
      float4 bv = *(const float4*)&Bs[k][tj4];
      acc[0][0] += av.x * bv.x; acc[0][1] += av.x * bv.y; acc[0][2] += av.x * bv.z; acc[0][3] += av.x * bv.w;
      acc[1][0] += av.y * bv.x; acc[1][1] += av.y * bv.y; acc[1][2] += av.y * bv.z; acc[1][3] += av.y * bv.w;
      acc[2][0] += av.z * bv.x; acc[2][1] += av.z * bv.y; acc[2][2] += av.z * bv.z; acc[2][3] += av.z * bv.w;
      acc[3][0] += av.w * bv.x; acc[3][1] += av.w * bv.y; acc[3][2] += av.w * bv.z; acc[3][3] += av.w * bv.w;
    }
    __syncthreads();
  }
  float4 bb;
  if (bias) bb = *(const float4*)&bias[j0 + tj4];
  else { bb.x = bb.y = bb.z = bb.w = 0.f; }
#pragma unroll
  for (int ii = 0; ii < 4; ++ii) {
    float4 o;
    o.x = acc[ii][0] + bb.x; o.y = acc[ii][1] + bb.y;
    o.z = acc[ii][2] + bb.z; o.w = acc[ii][3] + bb.w;
    *(float4*)&C[(size_t)(i0 + ti4 + ii) * 256 + j0 + tj4] = o;
  }
}

// ---------------------------------------------------------------------------
// k_edges: e_src/e_dst [B][H][N] from h [B][N][H*D]
// block = 256 threads = 4 waves, each wave one row
__global__ __launch_bounds__(256) void k_edges(
    const float* __restrict__ h, const float* __restrict__ a_src,
    const float* __restrict__ a_dst, float* __restrict__ esrc, float* __restrict__ edst)
{
  __shared__ float as_[256], ad_[256];
  int t = threadIdx.x;
  as_[t] = a_src[t];
  ad_[t] = a_dst[t];
  __syncthreads();
  int w = t >> 6, l = t & 63;
  int row = blockIdx.x * 4 + w;  // b*1024+n
  const float* x = h + (size_t)row * 256;
  float ps[4], pd[4];
#pragma unroll
  for (int hh = 0; hh < 4; ++hh) {
    float v = x[hh * 64 + l];
    ps[hh] = v * as_[hh * 64 + l];
    pd[hh] = v * ad_[hh * 64 + l];
  }
#pragma unroll
  for (int hh = 0; hh < 4; ++hh) {
    for (int o = 32; o; o >>= 1) {
      ps[hh] += __shfl_down(ps[hh], o);
      pd[hh] += __shfl_down(pd[hh], o);
    }
  }
  if (l == 0) {
    int b = row >> 10, n = row & 1023;
#pragma unroll
    for (int hh = 0; hh < 4; ++hh) {
      esrc[((b * 4 + hh) << 10) + n] = ps[hh];
      edst[((b * 4 + hh) << 10) + n] = pd[hh];
    }
  }
}

// ---------------------------------------------------------------------------
// k_emax: M[b][h] = max over valid j of e_dst[b][h][j]
__global__ __launch_bounds__(256) void k_emax(
    const float* __restrict__ edst, const float* __restrict__ mask, float* __restrict__ Mmax)
{
  int bh = blockIdx.x;  // b*4+h
  int b = bh >> 2;
  int t = threadIdx.x;
  float v = -1e30f;
  for (int j = t; j < 1024; j += 256)
    if (mask[(b << 10) + j] != 0.f) v = fmaxf(v, edst[(bh << 10) + j]);
  for (int o = 32; o; o >>= 1) v = fmaxf(v, __shfl_down(v, o));
  __shared__ float red[4];
  if ((t & 63) == 0) red[t >> 6] = v;
  __syncthreads();
  if (t == 0) Mmax[bh] = fmaxf(fmaxf(red[0], red[1]), fmaxf(red[2], red[3]));
}

// ---------------------------------------------------------------------------
// k_attn: fused attention aggregation + epilogue.
// Block: 256 threads (wave = head, lane = d), 16 i-rows per block.
// LAYER 1: concat + residual + LN(256) + relu -> out [B][N][256]
// LAYER 2: head-mean + LN(64) + relu -> out [B][N][64]
template <int LAYER>
__global__ __launch_bounds__(256) void k_attn(
    const float* __restrict__ h, const float* __restrict__ esrc,
    const float* __restrict__ edst, const float* __restrict__ Mmax,
    const float* __restrict__ mask, const float* __restrict__ resid,
    const float* __restrict__ g, const float* __restrict__ be,
    float* __restrict__ out)
{
  __shared__ float wT[4][64][20];  // [h][j][i], pad 20 -> 16B-aligned rows
  __shared__ float y[16][256];
  __shared__ float esrcL[16][4], mL[16][4], sInv[16][4];
  __shared__ float maskL[16], MhL[4];
  __shared__ float statM[16], statR[16];

  int t = threadIdx.x;
  int hID = t >> 6, l = t & 63;
  int b = blockIdx.x >> 6, it = blockIdx.x & 63;
  int i0 = it << 4;

  if (t < 16) maskL[t] = mask[(b << 10) + i0 + t];
  if (t < 4) MhL[t] = Mmax[(b << 2) + t];
  if (t < 64) {
    int ii = t >> 2, hh = t & 3;
    esrcL[ii][hh] = esrc[(((b << 2) + hh) << 10) + i0 + ii];
  }
  __syncthreads();
  if (t < 64) {
    int ii = t >> 2, hh = t & 3;
    float m = 0.f;
    if (maskL[ii] != 0.f) {
      float v = esrcL[ii][hh] + MhL[hh];
      m = v > 0.f ? v : 0.2f * v;
    }
    mL[ii][hh] = m;
  }
  __syncthreads();

  float acc[16], sp[16];
#pragma unroll
  for (int i = 0; i < 16; ++i) { acc[i] = 0.f; sp[i] = 0.f; }

  const float* hb_base = h + ((size_t)(b << 10)) * 256 + t;
  const float* ej_base = edst + (((b << 2) + hID) << 10);
  const float* mk_base = mask + (b << 10);

  for (int c = 0; c < 16; ++c) {
    int j0 = c << 6;
    float ejv = ej_base[j0 + l];
    float mj = mk_base[j0 + l];
#pragma unroll
    for (int i = 0; i < 16; ++i) {
      float w;
      if (maskL[i] != 0.f) {
        float v = esrcL[i][hID] + ejv;
        v = v > 0.f ? v : 0.2f * v;
        w = (mj != 0.f) ? __expf(v - mL[i][hID]) : 0.f;
      } else {
        w = 1.f;  // invalid row -> uniform over ALL j (matches reference)
      }
      wT[hID][l][i] = w;
      sp[i] += w;
    }
    __syncthreads();
    const float* hp = hb_base + (size_t)j0 * 256;
#pragma unroll 8
    for (int jj = 0; jj < 64; ++jj) {
      float hv = hp[(size_t)jj * 256];
      const float4* wp = (const float4*)(&wT[hID][jj][0]);
      float4 w0 = wp[0], w1 = wp[1], w2 = wp[2], w3 = wp[3];
      acc[0] += w0.x * hv;  acc[1] += w0.y * hv;  acc[2] += w0.z * hv;  acc[3] += w0.w * hv;
      acc[4] += w1.x * hv;  acc[5] += w1.y * hv;  acc[6] += w1.z * hv;  acc[7] += w1.w * hv;
      acc[8] += w2.x * hv;  acc[9] += w2.y * hv;  acc[10] += w2.z * hv; acc[11] += w2.w * hv;
      acc[12] += w3.x * hv; acc[13] += w3.y * hv; acc[14] += w3.z * hv; acc[15] += w3.w * hv;
    }
    __syncthreads();
  }

  // softmax denominators: reduce sp over the 64 lanes of each wave
#pragma unroll
  for (int i = 0; i < 16; ++i) {
    float v = sp[i];
    for (int o = 32; o; o >>= 1) v += __shfl_xor(v, o);
    if (l == 0) sInv[i][hID] = 1.f / v;
  }
  __syncthreads();

  if (LAYER == 1) {
#pragma unroll
    for (int i = 0; i < 16; ++i)
      y[i][t] = acc[i] * sInv[i][hID] + resid[((size_t)(b * 1024 + i0 + i)) * 256 + t];
    __syncthreads();
#pragma unroll
    for (int rr = 0; rr < 4; ++rr) {
      int i = (rr << 2) + hID;
      float v0 = y[i][l], v1 = y[i][64 + l], v2 = y[i][128 + l], v3 = y[i][192 + l];
      float s = v0 + v1 + v2 + v3;
      float q = v0 * v0 + v1 * v1 + v2 * v2 + v3 * v3;
      for (int o = 32; o; o >>= 1) { s += __shfl_xor(s, o); q += __shfl_xor(q, o); }
      if (l == 0) {
        float mean = s * (1.f / 256.f);
        float var = q * (1.f / 256.f) - mean * mean;
        statM[i] = mean;
        statR[i] = rsqrtf(var + 1e-5f);
      }
    }
    __syncthreads();
#pragma unroll
    for (int i = 0; i < 16; ++i) {
      float yv = y[i][t];
      float o_ = (yv - statM[i]) * statR[i] * g[t] + be[t];
      out[((size_t)(b * 1024 + i0 + i)) * 256 + t] = fmaxf(o_, 0.f);
    }
  } else {
#pragma unroll
    for (int i = 0; i < 16; ++i) y[i][t] = acc[i] * sInv[i][hID];
    __syncthreads();
#pragma unroll
    for (int rr = 0; rr < 4; ++rr) {
      int i = (rr << 2) + hID;
      float v = 0.25f * (y[i][l] + y[i][64 + l] + y[i][128 + l] + y[i][192 + l]);
      float s = v, q = v * v;
      for (int o = 32; o; o >>= 1) { s += __shfl_xor(s, o); q += __shfl_xor(q, o); }
      float mean = s * (1.f / 64.f);
      float var = q * (1.f / 64.f) - mean * mean;
      float rstd = rsqrtf(var + 1e-5f);
      float o_ = (v - mean) * rstd * g[l] + be[l];
      out[((size_t)(b * 1024 + i0 + i)) * 64 + l] = fmaxf(o_, 0.f);
    }
  }
}

// ---------------------------------------------------------------------------
// k_myemb: my_emb = relu(h2[b, idx[b]] @ Wm + bm), one block
__global__ __launch_bounds__(256) void k_myemb(
    const float* __restrict__ h2, const int* __restrict__ idx,
    const float* __restrict__ Wm, const float* __restrict__ bm, float* __restrict__ out)
{
  __shared__ float row[64];
  int t = threadIdx.x;
  for (int b = 0; b < 8; ++b) {
    int n = idx[b];
    if (t < 64) row[t] = h2[((size_t)(b * 1024 + n)) * 64 + t];
    __syncthreads();
    float acc = bm[t];
#pragma unroll
    for (int d = 0; d < 64; ++d) acc += row[d] * Wm[d * 256 + t];
    out[2097152 + b * 256 + t] = fmaxf(acc, 0.f);
    __syncthreads();
  }
}

// ---------------------------------------------------------------------------
extern "C" void kernel_launch(void* const* d_in, const int* in_sizes, int n_in,
                              void* d_out, int out_size, void* d_ws, size_t ws_size,
                              hipStream_t stream) {
  const float* agents = (const float*)d_in[0];
  const int* my_id = (const int*)d_in[1];
  const float* Wp = (const float*)d_in[2];
  const float* bp = (const float*)d_in[3];
  const float* W1 = (const float*)d_in[4];
  const float* a_src1 = (const float*)d_in[5];
  const float* a_dst1 = (const float*)d_in[6];
  const float* ln1_g = (const float*)d_in[7];
  const float* ln1_b = (const float*)d_in[8];
  const float* W2 = (const float*)d_in[9];
  const float* a_src2 = (const float*)d_in[10];
  const float* a_dst2 = (const float*)d_in[11];
  const float* ln2_g = (const float*)d_in[12];
  const float* ln2_b = (const float*)d_in[13];
  const float* Wa = (const float*)d_in[14];
  const float* ba = (const float*)d_in[15];
  const float* Wm = (const float*)d_in[16];
  const float* bm = (const float*)d_in[17];
  float* out = (float*)d_out;

  float* W = (float*)d_ws;
  float* mask = W;                    // 8192
  float* Mmax = W + 8192;             // 32
  int* idx = (int*)(W + 8224);        // 8 ints
  float* esrc = W + 16384;            // 32768  [B][H][N]
  float* edst = W + 49152;            // 32768
  float* proj = W + 81920;            // 2097152
  float* htmp = W + 2179072;          // 2097152
  float* h1 = W + 4276224;            // 2097152
  float* h2 = W + 6373376;            // 524288

  hipMemsetAsync(idx, 0x7F, 8 * sizeof(int), stream);
  k_proj<<<8192, 256, 0, stream>>>(agents, my_id, Wp, bp, proj, mask, idx);

  // ---- layer 1 ----
  k_gemm<<<512, 256, 0, stream>>>(proj, W1, nullptr, htmp, 256);
  k_edges<<<2048, 256, 0, stream>>>(htmp, a_src1, a_dst1, esrc, edst);
  k_emax<<<32, 256, 0, stream>>>(edst, mask, Mmax);
  k_attn<1><<<512, 256, 0, stream>>>(htmp, esrc, edst, Mmax, mask, proj, ln1_g, ln1_b, h1);

  // ---- layer 2 ----
  k_gemm<<<512, 256, 0, stream>>>(h1, W2, nullptr, htmp, 256);
  k_edges<<<2048, 256, 0, stream>>>(htmp, a_src2, a_dst2, esrc, edst);
  k_emax<<<32, 256, 0, stream>>>(edst, mask, Mmax);
  k_attn<2><<<512, 256, 0, stream>>>(htmp, esrc, edst, Mmax, mask, proj, ln2_g, ln2_b, h2);

  // ---- heads ----
  k_gemm<<<512, 256, 0, stream>>>(h2, Wa, ba, out, 64);
  k_myemb<<<1, 256, 0, stream>>>(h2, idx, Wm, bm, out);
}

// Round 5
// 356.018 us; speedup vs baseline: 2.2992x; 2.2992x over previous
//
#include <hip/hip_runtime.h>
#include <hip/hip_bf16.h>

// Sizes (fixed by the problem)
// B=8, N=1024, hidden=256, heads H=4, d_head D=64, entity_dim=31, merged=35

// ---------------------------------------------------------------------------
// k_proj: merged one-hot projection + mask + my-idx
__global__ __launch_bounds__(256) void k_proj(
    const float* __restrict__ agents, const int* __restrict__ my_id,
    const float* __restrict__ Wp, const float* __restrict__ bp,
    float* __restrict__ proj, float* __restrict__ mask, int* __restrict__ idx)
{
  int blk = blockIdx.x;
  int b = blk >> 10, n = blk & 1023;
  __shared__ float arow[32];
  int t = threadIdx.x;
  if (t < 31) arow[t] = agents[((size_t)(b * 1024 + n)) * 31 + t];
  __syncthreads();
  float id = arow[0];
  int npc = (int)arow[1];
  float acc = bp[t] + id * Wp[t] + Wp[(1 + npc) * 256 + t];
#pragma unroll
  for (int c = 2; c < 31; ++c) acc += arow[c] * Wp[(4 + c) * 256 + t];
  proj[((size_t)(b * 1024 + n)) * 256 + t] = acc;
  if (t == 0) {
    mask[b * 1024 + n] = (id != 0.f) ? 1.f : 0.f;
    if (id == (float)my_id[b]) atomicMin(&idx[b], n);
  }
}

// ---------------------------------------------------------------------------
// Generic fp32 GEMM: C[M x 256] = A[M x K] * B[K x 256] (+bias), M = 8192
__global__ __launch_bounds__(256) void k_gemm(
    const float* __restrict__ A, const float* __restrict__ B,
    const float* __restrict__ bias, float* __restrict__ C, int K)
{
  __shared__ float As[64][68];  // [k][i]
  __shared__ float Bs[64][68];  // [k][j]
  int tid = threadIdx.x;
  int bi = blockIdx.x >> 2;   // 0..127
  int bj = blockIdx.x & 3;    // 0..3
  int i0 = bi << 6, j0 = bj << 6;
  int ti4 = (tid & 15) << 2;
  int tj4 = (tid >> 4) << 2;
  int r = tid >> 2;
  int c0 = (tid & 3) << 4;
  float acc[4][4];
#pragma unroll
  for (int a = 0; a < 4; ++a)
#pragma unroll
    for (int q = 0; q < 4; ++q) acc[a][q] = 0.f;

  for (int k0 = 0; k0 < K; k0 += 64) {
    const float4* Ap4 = (const float4*)(A + (size_t)(i0 + r) * K + k0 + c0);
    float4 aa0 = Ap4[0], aa1 = Ap4[1], aa2 = Ap4[2], aa3 = Ap4[3];
    As[c0 + 0][r] = aa0.x; As[c0 + 1][r] = aa0.y; As[c0 + 2][r] = aa0.z; As[c0 + 3][r] = aa0.w;
    As[c0 + 4][r] = aa1.x; As[c0 + 5][r] = aa1.y; As[c0 + 6][r] = aa1.z; As[c0 + 7][r] = aa1.w;
    As[c0 + 8][r] = aa2.x; As[c0 + 9][r] = aa2.y; As[c0 +10][r] = aa2.z; As[c0 +11][r] = aa2.w;
    As[c0 +12][r] = aa3.x; As[c0 +13][r] = aa3.y; As[c0 +14][r] = aa3.z; As[c0 +15][r] = aa3.w;
    const float4* Bp4 = (const float4*)(B + (size_t)(k0 + r) * 256 + j0 + c0);
    float4 bb0 = Bp4[0], bb1 = Bp4[1], bb2 = Bp4[2], bb3 = Bp4[3];
    *(float4*)&Bs[r][c0 + 0]  = bb0;
    *(float4*)&Bs[r][c0 + 4]  = bb1;
    *(float4*)&Bs[r][c0 + 8]  = bb2;
    *(float4*)&Bs[r][c0 + 12] = bb3;
    __syncthreads();
#pragma unroll
    for (int k = 0; k < 64; ++k) {
      float4 av = *(const float4*)&As[k][ti4];
      float4 bv = *(const float4*)&Bs[k][tj4];
      acc[0][0] += av.x * bv.x; acc[0][1] += av.x * bv.y; acc[0][2] += av.x * bv.z; acc[0][3] += av.x * bv.w;
      acc[1][0] += av.y * bv.x; acc[1][1] += av.y * bv.y; acc[1][2] += av.y * bv.z; acc[1][3] += av.y * bv.w;
      acc[2][0] += av.z * bv.x; acc[2][1] += av.z * bv.y; acc[2][2] += av.z * bv.z; acc[2][3] += av.z * bv.w;
      acc[3][0] += av.w * bv.x; acc[3][1] += av.w * bv.y; acc[3][2] += av.w * bv.z; acc[3][3] += av.w * bv.w;
    }
    __syncthreads();
  }
  float4 bb;
  if (bias) bb = *(const float4*)&bias[j0 + tj4];
  else { bb.x = bb.y = bb.z = bb.w = 0.f; }
#pragma unroll
  for (int ii = 0; ii < 4; ++ii) {
    float4 o;
    o.x = acc[ii][0] + bb.x; o.y = acc[ii][1] + bb.y;
    o.z = acc[ii][2] + bb.z; o.w = acc[ii][3] + bb.w;
    *(float4*)&C[(size_t)(i0 + ti4 + ii) * 256 + j0 + tj4] = o;
  }
}

// ---------------------------------------------------------------------------
// k_edges: e_src/e_dst [B][H][N]
__global__ __launch_bounds__(256) void k_edges(
    const float* __restrict__ h, const float* __restrict__ a_src,
    const float* __restrict__ a_dst, float* __restrict__ esrc, float* __restrict__ edst)
{
  __shared__ float as_[256], ad_[256];
  int t = threadIdx.x;
  as_[t] = a_src[t];
  ad_[t] = a_dst[t];
  __syncthreads();
  int w = t >> 6, l = t & 63;
  int row = blockIdx.x * 4 + w;
  const float* x = h + (size_t)row * 256;
  float ps[4], pd[4];
#pragma unroll
  for (int hh = 0; hh < 4; ++hh) {
    float v = x[hh * 64 + l];
    ps[hh] = v * as_[hh * 64 + l];
    pd[hh] = v * ad_[hh * 64 + l];
  }
#pragma unroll
  for (int hh = 0; hh < 4; ++hh) {
    for (int o = 32; o; o >>= 1) {
      ps[hh] += __shfl_down(ps[hh], o);
      pd[hh] += __shfl_down(pd[hh], o);
    }
  }
  if (l == 0) {
    int b = row >> 10, n = row & 1023;
#pragma unroll
    for (int hh = 0; hh < 4; ++hh) {
      esrc[((b * 4 + hh) << 10) + n] = ps[hh];
      edst[((b * 4 + hh) << 10) + n] = pd[hh];
    }
  }
}

// ---------------------------------------------------------------------------
__global__ __launch_bounds__(256) void k_emax(
    const float* __restrict__ edst, const float* __restrict__ mask, float* __restrict__ Mmax)
{
  int bh = blockIdx.x;
  int b = bh >> 2;
  int t = threadIdx.x;
  float v = -1e30f;
  for (int j = t; j < 1024; j += 256)
    if (mask[(b << 10) + j] != 0.f) v = fmaxf(v, edst[(bh << 10) + j]);
  for (int o = 32; o; o >>= 1) v = fmaxf(v, __shfl_down(v, o));
  __shared__ float red[4];
  if ((t & 63) == 0) red[t >> 6] = v;
  __syncthreads();
  if (t == 0) Mmax[bh] = fmaxf(fmaxf(red[0], red[1]), fmaxf(red[2], red[3]));
}

// ---------------------------------------------------------------------------
// k_attn: fused attention aggregation + epilogue.
// ITILE=8 rows per block -> grid = B * 128 = 1024 blocks (4 blocks/CU).
// XCD-aware: b = blockIdx.x & 7 so each XCD's L2 caches exactly one batch's h.
template <int LAYER>
__global__ __launch_bounds__(256) void k_attn(
    const float* __restrict__ h, const float* __restrict__ esrc,
    const float* __restrict__ edst, const float* __restrict__ Mmax,
    const float* __restrict__ mask, const float* __restrict__ resid,
    const float* __restrict__ g, const float* __restrict__ be,
    float* __restrict__ out)
{
  __shared__ float wT[4][64][12];  // [h][j][i], row = 48B (16B-aligned)
  __shared__ float y[8][256];
  __shared__ float esrcL[8][4], mL[8][4], sInv[8][4];
  __shared__ float maskL[8], MhL[4];
  __shared__ float statM[8], statR[8];

  int t = threadIdx.x;
  int hID = t >> 6, l = t & 63;
  int b = blockIdx.x & 7;         // one b per XCD
  int it = blockIdx.x >> 3;       // 0..127
  int i0 = it << 3;

  if (t < 8) maskL[t] = mask[(b << 10) + i0 + t];
  if (t < 4) MhL[t] = Mmax[(b << 2) + t];
  if (t < 32) {
    int ii = t >> 2, hh = t & 3;
    esrcL[ii][hh] = esrc[(((b << 2) + hh) << 10) + i0 + ii];
  }
  __syncthreads();
  if (t < 32) {
    int ii = t >> 2, hh = t & 3;
    float m = 0.f;
    if (maskL[ii] != 0.f) {
      float v = esrcL[ii][hh] + MhL[hh];
      m = v > 0.f ? v : 0.2f * v;
    }
    mL[ii][hh] = m;
  }
  __syncthreads();

  // hoist per-row params into registers
  float esr[8], mr[8], mskr[8];
#pragma unroll
  for (int i = 0; i < 8; ++i) {
    esr[i] = esrcL[i][hID];
    mr[i] = mL[i][hID];
    mskr[i] = maskL[i];
  }

  float acc[8], sp[8];
#pragma unroll
  for (int i = 0; i < 8; ++i) { acc[i] = 0.f; sp[i] = 0.f; }

  const float* hb_base = h + ((size_t)(b << 10)) * 256 + t;
  const float* ej_base = edst + (((b << 2) + hID) << 10);
  const float* mk_base = mask + (b << 10);

  for (int c = 0; c < 16; ++c) {
    int j0 = c << 6;
    float ejv = ej_base[j0 + l];
    float mj = mk_base[j0 + l];
#pragma unroll
    for (int i = 0; i < 8; ++i) {
      float w;
      if (mskr[i] != 0.f) {
        float v = esr[i] + ejv;
        v = v > 0.f ? v : 0.2f * v;
        w = (mj != 0.f) ? __expf(v - mr[i]) : 0.f;
      } else {
        w = 1.f;  // invalid row -> uniform over ALL j (matches reference)
      }
      wT[hID][l][i] = w;
      sp[i] += w;
    }
    __syncthreads();
    const float* hp = hb_base + (size_t)j0 * 256;
#pragma unroll 16
    for (int jj = 0; jj < 64; ++jj) {
      float hv = hp[(size_t)jj * 256];
      const float4* wp = (const float4*)(&wT[hID][jj][0]);
      float4 w0 = wp[0], w1 = wp[1];
      acc[0] += w0.x * hv; acc[1] += w0.y * hv; acc[2] += w0.z * hv; acc[3] += w0.w * hv;
      acc[4] += w1.x * hv; acc[5] += w1.y * hv; acc[6] += w1.z * hv; acc[7] += w1.w * hv;
    }
    __syncthreads();
  }

  // softmax denominators
#pragma unroll
  for (int i = 0; i < 8; ++i) {
    float v = sp[i];
    for (int o = 32; o; o >>= 1) v += __shfl_xor(v, o);
    if (l == 0) sInv[i][hID] = 1.f / v;
  }
  __syncthreads();

  if (LAYER == 1) {
#pragma unroll
    for (int i = 0; i < 8; ++i)
      y[i][t] = acc[i] * sInv[i][hID] + resid[((size_t)(b * 1024 + i0 + i)) * 256 + t];
    __syncthreads();
#pragma unroll
    for (int rr = 0; rr < 2; ++rr) {
      int i = (rr << 2) + hID;
      float v0 = y[i][l], v1 = y[i][64 + l], v2 = y[i][128 + l], v3 = y[i][192 + l];
      float s = v0 + v1 + v2 + v3;
      float q = v0 * v0 + v1 * v1 + v2 * v2 + v3 * v3;
      for (int o = 32; o; o >>= 1) { s += __shfl_xor(s, o); q += __shfl_xor(q, o); }
      if (l == 0) {
        float mean = s * (1.f / 256.f);
        float var = q * (1.f / 256.f) - mean * mean;
        statM[i] = mean;
        statR[i] = rsqrtf(var + 1e-5f);
      }
    }
    __syncthreads();
#pragma unroll
    for (int i = 0; i < 8; ++i) {
      float yv = y[i][t];
      float o_ = (yv - statM[i]) * statR[i] * g[t] + be[t];
      out[((size_t)(b * 1024 + i0 + i)) * 256 + t] = fmaxf(o_, 0.f);
    }
  } else {
#pragma unroll
    for (int i = 0; i < 8; ++i) y[i][t] = acc[i] * sInv[i][hID];
    __syncthreads();
#pragma unroll
    for (int rr = 0; rr < 2; ++rr) {
      int i = (rr << 2) + hID;
      float v = 0.25f * (y[i][l] + y[i][64 + l] + y[i][128 + l] + y[i][192 + l]);
      float s = v, q = v * v;
      for (int o = 32; o; o >>= 1) { s += __shfl_xor(s, o); q += __shfl_xor(q, o); }
      float mean = s * (1.f / 64.f);
      float var = q * (1.f / 64.f) - mean * mean;
      float rstd = rsqrtf(var + 1e-5f);
      float o_ = (v - mean) * rstd * g[l] + be[l];
      out[((size_t)(b * 1024 + i0 + i)) * 64 + l] = fmaxf(o_, 0.f);
    }
  }
}

// ---------------------------------------------------------------------------
__global__ __launch_bounds__(256) void k_myemb(
    const float* __restrict__ h2, const int* __restrict__ idx,
    const float* __restrict__ Wm, const float* __restrict__ bm, float* __restrict__ out)
{
  __shared__ float row[64];
  int t = threadIdx.x;
  for (int b = 0; b < 8; ++b) {
    int n = idx[b];
    if (t < 64) row[t] = h2[((size_t)(b * 1024 + n)) * 64 + t];
    __syncthreads();
    float acc = bm[t];
#pragma unroll
    for (int d = 0; d < 64; ++d) acc += row[d] * Wm[d * 256 + t];
    out[2097152 + b * 256 + t] = fmaxf(acc, 0.f);
    __syncthreads();
  }
}

// ---------------------------------------------------------------------------
extern "C" void kernel_launch(void* const* d_in, const int* in_sizes, int n_in,
                              void* d_out, int out_size, void* d_ws, size_t ws_size,
                              hipStream_t stream) {
  const float* agents = (const float*)d_in[0];
  const int* my_id = (const int*)d_in[1];
  const float* Wp = (const float*)d_in[2];
  const float* bp = (const float*)d_in[3];
  const float* W1 = (const float*)d_in[4];
  const float* a_src1 = (const float*)d_in[5];
  const float* a_dst1 = (const float*)d_in[6];
  const float* ln1_g = (const float*)d_in[7];
  const float* ln1_b = (const float*)d_in[8];
  const float* W2 = (const float*)d_in[9];
  const float* a_src2 = (const float*)d_in[10];
  const float* a_dst2 = (const float*)d_in[11];
  const float* ln2_g = (const float*)d_in[12];
  const float* ln2_b = (const float*)d_in[13];
  const float* Wa = (const float*)d_in[14];
  const float* ba = (const float*)d_in[15];
  const float* Wm = (const float*)d_in[16];
  const float* bm = (const float*)d_in[17];
  float* out = (float*)d_out;

  float* W = (float*)d_ws;
  float* mask = W;                    // 8192
  float* Mmax = W + 8192;             // 32
  int* idx = (int*)(W + 8224);        // 8 ints
  float* esrc = W + 16384;            // 32768  [B][H][N]
  float* edst = W + 49152;            // 32768
  float* proj = W + 81920;            // 2097152
  float* htmp = W + 2179072;          // 2097152
  float* h1 = W + 4276224;            // 2097152
  float* h2 = W + 6373376;            // 524288

  hipMemsetAsync(idx, 0x7F, 8 * sizeof(int), stream);
  k_proj<<<8192, 256, 0, stream>>>(agents, my_id, Wp, bp, proj, mask, idx);

  // ---- layer 1 ----
  k_gemm<<<512, 256, 0, stream>>>(proj, W1, nullptr, htmp, 256);
  k_edges<<<2048, 256, 0, stream>>>(htmp, a_src1, a_dst1, esrc, edst);
  k_emax<<<32, 256, 0, stream>>>(edst, mask, Mmax);
  k_attn<1><<<1024, 256, 0, stream>>>(htmp, esrc, edst, Mmax, mask, proj, ln1_g, ln1_b, h1);

  // ---- layer 2 ----
  k_gemm<<<512, 256, 0, stream>>>(h1, W2, nullptr, htmp, 256);
  k_edges<<<2048, 256, 0, stream>>>(htmp, a_src2, a_dst2, esrc, edst);
  k_emax<<<32, 256, 0, stream>>>(edst, mask, Mmax);
  k_attn<2><<<1024, 256, 0, stream>>>(htmp, esrc, edst, Mmax, mask, proj, ln2_g, ln2_b, h2);

  // ---- heads ----
  k_gemm<<<512, 256, 0, stream>>>(h2, Wa, ba, out, 64);
  k_myemb<<<1, 256, 0, stream>>>(h2, idx, Wm, bm, out);
}